// Round 1
// baseline (210.082 us; speedup 1.0000x reference)
//
#include <hip/hip_runtime.h>
#include <hip/hip_bf16.h>

#define T_LEN 2048
#define NBATCH 32

typedef __bf16 bf16x8 __attribute__((ext_vector_type(8)));
typedef float f32x4 __attribute__((ext_vector_type(4)));

__device__ __forceinline__ unsigned short f2bf(float f) {
  return __builtin_bit_cast(unsigned short, __float2bfloat16(f));
}
__device__ __forceinline__ unsigned int pk2(float a, float b) {
  return (unsigned int)f2bf(a) | ((unsigned int)f2bf(b) << 16);
}
__device__ __forceinline__ bf16x8 ld16(const void* p) {
  return __builtin_bit_cast(bf16x8, *(const uint4*)p);
}

// ---------------- Kernel 0: W -> Wt3 bf16 [192][384] (col-major over N) --------
__global__ __launch_bounds__(256) void k_wprep(const float* __restrict__ Wq,
                                               const float* __restrict__ Wk,
                                               const float* __restrict__ Wv,
                                               unsigned short* __restrict__ Wt3) {
  int idx = blockIdx.x * 256 + threadIdx.x;   // 0 .. 192*384-1
  if (idx >= 192 * 384) return;
  int c = idx / 384;          // output col 0..191
  int k = idx % 384;          // k dim
  const float* W = (c < 64) ? Wq : ((c < 128) ? Wk : Wv);
  Wt3[idx] = f2bf(W[k * 64 + (c & 63)]);
}

// ---------------- Kernel 1: QKV projection (MFMA bf16) -------------------------
// x fp32 [B*T][384] -> Q,K bf16 [B*T][64], VT bf16 [B][64][T]
__global__ __launch_bounds__(256) void k_proj(const float* __restrict__ x,
                                              const unsigned short* __restrict__ Wt3,
                                              unsigned short* __restrict__ Qb,
                                              unsigned short* __restrict__ Kb,
                                              unsigned short* __restrict__ VTb) {
  __shared__ __align__(16) unsigned short xs[128 * 32];   // swizzled
  __shared__ __align__(16) unsigned short wt[192 * 32];   // swizzled
  const int tid = threadIdx.x;
  const int lane = tid & 63, w = tid >> 6;
  const int g = lane >> 4, lr = lane & 15;
  const long row0 = (long)blockIdx.x * 128;

  f32x4 acc[2][12] = {};

  for (int ks = 0; ks < 12; ++ks) {
    const int k0 = ks * 32;
    __syncthreads();
    // stage x tile [128][32] fp32->bf16
    {
      int r = tid >> 1, c0 = (tid & 1) * 16;
      const float4* src = reinterpret_cast<const float4*>(&x[(row0 + r) * 384 + k0 + c0]);
      float4 f0 = src[0], f1 = src[1], f2 = src[2], f3 = src[3];
      uint4 u0, u1;
      u0.x = pk2(f0.x, f0.y); u0.y = pk2(f0.z, f0.w);
      u0.z = pk2(f1.x, f1.y); u0.w = pk2(f1.z, f1.w);
      u1.x = pk2(f2.x, f2.y); u1.y = pk2(f2.z, f2.w);
      u1.z = pk2(f3.x, f3.y); u1.w = pk2(f3.z, f3.w);
      int b0 = (r * 64 + c0 * 2) ^ ((r & 7) << 4);
      int b1 = (r * 64 + c0 * 2 + 16) ^ ((r & 7) << 4);
      *reinterpret_cast<uint4*>((char*)xs + b0) = u0;
      *reinterpret_cast<uint4*>((char*)xs + b1) = u1;
    }
    // stage Wt3 tile [192 cols][32 k]
#pragma unroll
    for (int j = 0; j < 3; ++j) {
      int chunk = tid + 256 * j;        // 0..767
      int r = chunk >> 2, c8 = chunk & 3;
      uint4 d = *reinterpret_cast<const uint4*>(&Wt3[r * 384 + k0 + c8 * 8]);
      int b = (r * 64 + c8 * 16) ^ ((r & 7) << 4);
      *reinterpret_cast<uint4*>((char*)wt + b) = d;
    }
    __syncthreads();

    bf16x8 a[2];
#pragma unroll
    for (int mt = 0; mt < 2; ++mt) {
      int r = w * 32 + mt * 16 + lr;
      a[mt] = ld16((char*)xs + ((r * 64 + g * 16) ^ ((r & 7) << 4)));
    }
#pragma unroll
    for (int n = 0; n < 12; ++n) {
      int r = n * 16 + lr;
      bf16x8 bb = ld16((char*)wt + ((r * 64 + g * 16) ^ ((r & 7) << 4)));
      acc[0][n] = __builtin_amdgcn_mfma_f32_16x16x32_bf16(a[0], bb, acc[0][n], 0, 0, 0);
      acc[1][n] = __builtin_amdgcn_mfma_f32_16x16x32_bf16(a[1], bb, acc[1][n], 0, 0, 0);
    }
  }

  // epilogue: D layout col = lr, row = g*4 + rr
#pragma unroll
  for (int mt = 0; mt < 2; ++mt)
#pragma unroll
    for (int n = 0; n < 12; ++n)
#pragma unroll
      for (int rr = 0; rr < 4; ++rr) {
        long grow = row0 + w * 32 + mt * 16 + g * 4 + rr;
        int col = n * 16 + lr;
        unsigned short hv = f2bf(acc[mt][n][rr]);
        if (n < 4) {
          Qb[grow * 64 + col] = hv;
        } else if (n < 8) {
          Kb[grow * 64 + (col - 64)] = hv;
        } else {
          long bb_ = grow >> 11;          // / 2048
          long t = grow & 2047;
          VTb[(bb_ * 64 + (col - 128)) * 2048 + t] = hv;
        }
      }
}

// ---------------- Kernel 2: causal flash attention -----------------------------
__global__ __launch_bounds__(256) void k_attn(const unsigned short* __restrict__ Qb,
                                              const unsigned short* __restrict__ Kb,
                                              const unsigned short* __restrict__ VTb,
                                              float* __restrict__ out) {
  __shared__ __align__(16) unsigned short ksm[64 * 64];   // K tile [kv][hd], swizzled
  __shared__ __align__(16) unsigned short vsm[64 * 64];   // V^T tile [hd][kv], swizzled
  __shared__ __align__(16) unsigned short psm[4 * 16 * 64]; // per-wave P [16][64], swizzled

  const int tid = threadIdx.x;
  const int lane = tid & 63, w = tid >> 6;
  const int g = lane >> 4, lr = lane & 15;
  const int qt = (gridDim.x - 1) - blockIdx.x;   // reversed: long blocks first
  const int b = blockIdx.y;
  const int q0 = qt * 64;
  const int qrow0 = q0 + w * 16;

  // Q fragments (A operand): lane holds Q[qrow0+lr][c*32 + g*8 + i]
  bf16x8 qf[2];
#pragma unroll
  for (int c = 0; c < 2; ++c)
    qf[c] = ld16(&Qb[((long)(b * T_LEN + qrow0 + lr)) * 64 + c * 32 + g * 8]);

  f32x4 o[4] = {};
  float m_r[4], l_r[4];
#pragma unroll
  for (int r = 0; r < 4; ++r) { m_r[r] = -1e30f; l_r[r] = 0.f; }

  const int nkv = qt + 1;
  for (int t = 0; t < nkv; ++t) {
    const int kv0 = t * 64;
    __syncthreads();
    // stage K tile [64][64]
#pragma unroll
    for (int j = 0; j < 2; ++j) {
      int chunk = tid + 256 * j;          // 0..511
      int r = chunk >> 3, c8 = chunk & 7;
      uint4 d = *reinterpret_cast<const uint4*>(&Kb[((long)(b * T_LEN + kv0 + r)) * 64 + c8 * 8]);
      *reinterpret_cast<uint4*>((char*)ksm + ((r * 128 + c8 * 16) ^ ((r & 7) << 4))) = d;
    }
    // stage V^T tile [64 hd][64 kv] from VT[B][64][T]
#pragma unroll
    for (int j = 0; j < 2; ++j) {
      int chunk = tid + 256 * j;
      int r = chunk >> 3, c8 = chunk & 7;  // r = hd, c8*8 = kv offset
      uint4 d = *reinterpret_cast<const uint4*>(&VTb[((long)(b * 64 + r)) * 2048 + kv0 + c8 * 8]);
      *reinterpret_cast<uint4*>((char*)vsm + ((r * 128 + c8 * 16) ^ ((r & 7) << 4))) = d;
    }
    __syncthreads();

    // S = Q K^T
    f32x4 s[4] = {};
#pragma unroll
    for (int c = 0; c < 2; ++c)
#pragma unroll
      for (int n = 0; n < 4; ++n) {
        int r = n * 16 + lr;
        bf16x8 kf = ld16((char*)ksm + ((r * 128 + c * 64 + g * 16) ^ ((r & 7) << 4)));
        s[n] = __builtin_amdgcn_mfma_f32_16x16x32_bf16(qf[c], kf, s[n], 0, 0, 0);
      }

    // scale + causal mask (only diagonal tile needs masking)
    const bool diag = (t == qt);
#pragma unroll
    for (int n = 0; n < 4; ++n)
#pragma unroll
      for (int r = 0; r < 4; ++r) {
        float v = s[n][r] * 0.125f;
        if (diag) {
          int col = kv0 + n * 16 + lr;
          int rowq = qrow0 + g * 4 + r;
          if (col > rowq) v = -1e30f;
        }
        s[n][r] = v;
      }

    // online softmax (rows owned per (g, r); reduce across 16 lanes = cols)
    float pr[4][4];
#pragma unroll
    for (int r = 0; r < 4; ++r) {
      float mx = fmaxf(fmaxf(s[0][r], s[1][r]), fmaxf(s[2][r], s[3][r]));
      mx = fmaxf(mx, __shfl_xor(mx, 1));
      mx = fmaxf(mx, __shfl_xor(mx, 2));
      mx = fmaxf(mx, __shfl_xor(mx, 4));
      mx = fmaxf(mx, __shfl_xor(mx, 8));
      float mn = fmaxf(m_r[r], mx);
      float sc = exp2f((m_r[r] - mn) * 1.44269504f);
      m_r[r] = mn;
      float sum = 0.f;
#pragma unroll
      for (int n = 0; n < 4; ++n) {
        float p = exp2f((s[n][r] - mn) * 1.44269504f);
        pr[n][r] = p;
        sum += p;
      }
      sum += __shfl_xor(sum, 1);
      sum += __shfl_xor(sum, 2);
      sum += __shfl_xor(sum, 4);
      sum += __shfl_xor(sum, 8);
      l_r[r] = l_r[r] * sc + sum;
#pragma unroll
      for (int n = 0; n < 4; ++n) o[n][r] *= sc;
    }

    // write P (bf16) to this wave's LDS buffer, swizzled
    char* pbase = (char*)psm + w * 2048;
#pragma unroll
    for (int n = 0; n < 4; ++n)
#pragma unroll
      for (int r = 0; r < 4; ++r) {
        int rq = g * 4 + r;
        int col = n * 16 + lr;
        *(unsigned short*)(pbase + ((rq * 128 + col * 2) ^ ((rq & 7) << 4))) = f2bf(pr[n][r]);
      }

    // O += P V
    bf16x8 pf[2];
#pragma unroll
    for (int c = 0; c < 2; ++c)
      pf[c] = ld16(pbase + ((lr * 128 + c * 64 + g * 16) ^ ((lr & 7) << 4)));
#pragma unroll
    for (int c = 0; c < 2; ++c)
#pragma unroll
      for (int n = 0; n < 4; ++n) {
        int r = n * 16 + lr;
        bf16x8 vf = ld16((char*)vsm + ((r * 128 + c * 64 + g * 16) ^ ((r & 7) << 4)));
        o[n] = __builtin_amdgcn_mfma_f32_16x16x32_bf16(pf[c], vf, o[n], 0, 0, 0);
      }
  }

  // epilogue
#pragma unroll
  for (int r = 0; r < 4; ++r) {
    float inv = 1.0f / l_r[r];
#pragma unroll
    for (int n = 0; n < 4; ++n) {
      long rowg = (long)b * T_LEN + qrow0 + g * 4 + r;
      out[rowg * 64 + n * 16 + lr] = o[n][r] * inv;
    }
  }
}

// ---------------- launch -------------------------------------------------------
extern "C" void kernel_launch(void* const* d_in, const int* in_sizes, int n_in,
                              void* d_out, int out_size, void* d_ws, size_t ws_size,
                              hipStream_t stream) {
  const float* x  = (const float*)d_in[0];
  const float* Wq = (const float*)d_in[1];
  const float* Wk = (const float*)d_in[2];
  const float* Wv = (const float*)d_in[3];
  float* out = (float*)d_out;

  char* ws = (char*)d_ws;
  unsigned short* Wt3 = (unsigned short*)ws;                          // 294912 B
  unsigned short* Qb  = (unsigned short*)(ws + 0x80000);              // 8 MiB each
  unsigned short* Kb  = (unsigned short*)(ws + 0x80000 + 0x800000);
  unsigned short* VTb = (unsigned short*)(ws + 0x80000 + 0x1000000);

  k_wprep<<<dim3(288), dim3(256), 0, stream>>>(Wq, Wk, Wv, Wt3);
  k_proj<<<dim3(512), dim3(256), 0, stream>>>(x, Wt3, Qb, Kb, VTb);
  k_attn<<<dim3(32, 32), dim3(256), 0, stream>>>(Qb, Kb, VTb, out);
}

// Round 2
// 188.951 us; speedup vs baseline: 1.1118x; 1.1118x over previous
//
#include <hip/hip_runtime.h>
#include <hip/hip_bf16.h>

#define T_LEN 2048
#define NBATCH 32

typedef __bf16 bf16x8 __attribute__((ext_vector_type(8)));
typedef float f32x4 __attribute__((ext_vector_type(4)));

__device__ __forceinline__ unsigned short f2bf(float f) {
  return __builtin_bit_cast(unsigned short, __float2bfloat16(f));
}
__device__ __forceinline__ unsigned int pk2(float a, float b) {
  return (unsigned int)f2bf(a) | ((unsigned int)f2bf(b) << 16);
}
__device__ __forceinline__ bf16x8 ld16(const void* p) {
  return __builtin_bit_cast(bf16x8, *(const uint4*)p);
}

// ---------------- Kernel 0: W -> Wt3 bf16 [192][384] (col-major over N) --------
__global__ __launch_bounds__(256) void k_wprep(const float* __restrict__ Wq,
                                               const float* __restrict__ Wk,
                                               const float* __restrict__ Wv,
                                               unsigned short* __restrict__ Wt3) {
  int idx = blockIdx.x * 256 + threadIdx.x;   // 0 .. 192*384-1
  if (idx >= 192 * 384) return;
  int c = idx / 384;          // output col 0..191
  int k = idx % 384;          // k dim
  const float* W = (c < 64) ? Wq : ((c < 128) ? Wk : Wv);
  Wt3[idx] = f2bf(W[k * 64 + (c & 63)]);
}

// ---------------- Kernel 1: QKV projection (MFMA bf16) -------------------------
// x fp32 [B*T][384] -> Q,K bf16 [B*T][64], VT bf16 [B][64][T]
__global__ __launch_bounds__(256) void k_proj(const float* __restrict__ x,
                                              const unsigned short* __restrict__ Wt3,
                                              unsigned short* __restrict__ Qb,
                                              unsigned short* __restrict__ Kb,
                                              unsigned short* __restrict__ VTb) {
  __shared__ __align__(16) unsigned short xs[128 * 32];   // swizzled
  __shared__ __align__(16) unsigned short wt[192 * 32];   // swizzled
  const int tid = threadIdx.x;
  const int lane = tid & 63, w = tid >> 6;
  const int g = lane >> 4, lr = lane & 15;
  const long row0 = (long)blockIdx.x * 128;

  f32x4 acc[2][12] = {};

  for (int ks = 0; ks < 12; ++ks) {
    const int k0 = ks * 32;
    __syncthreads();
    // stage x tile [128][32] fp32->bf16
    {
      int r = tid >> 1, c0 = (tid & 1) * 16;
      const float4* src = reinterpret_cast<const float4*>(&x[(row0 + r) * 384 + k0 + c0]);
      float4 f0 = src[0], f1 = src[1], f2 = src[2], f3 = src[3];
      uint4 u0, u1;
      u0.x = pk2(f0.x, f0.y); u0.y = pk2(f0.z, f0.w);
      u0.z = pk2(f1.x, f1.y); u0.w = pk2(f1.z, f1.w);
      u1.x = pk2(f2.x, f2.y); u1.y = pk2(f2.z, f2.w);
      u1.z = pk2(f3.x, f3.y); u1.w = pk2(f3.z, f3.w);
      int b0 = (r * 64 + c0 * 2) ^ ((r & 7) << 4);
      int b1 = (r * 64 + c0 * 2 + 16) ^ ((r & 7) << 4);
      *reinterpret_cast<uint4*>((char*)xs + b0) = u0;
      *reinterpret_cast<uint4*>((char*)xs + b1) = u1;
    }
    // stage Wt3 tile [192 cols][32 k]
#pragma unroll
    for (int j = 0; j < 3; ++j) {
      int chunk = tid + 256 * j;        // 0..767
      int r = chunk >> 2, c8 = chunk & 3;
      uint4 d = *reinterpret_cast<const uint4*>(&Wt3[r * 384 + k0 + c8 * 8]);
      int b = (r * 64 + c8 * 16) ^ ((r & 7) << 4);
      *reinterpret_cast<uint4*>((char*)wt + b) = d;
    }
    __syncthreads();

    bf16x8 a[2];
#pragma unroll
    for (int mt = 0; mt < 2; ++mt) {
      int r = w * 32 + mt * 16 + lr;
      a[mt] = ld16((char*)xs + ((r * 64 + g * 16) ^ ((r & 7) << 4)));
    }
#pragma unroll
    for (int n = 0; n < 12; ++n) {
      int r = n * 16 + lr;
      bf16x8 bb = ld16((char*)wt + ((r * 64 + g * 16) ^ ((r & 7) << 4)));
      acc[0][n] = __builtin_amdgcn_mfma_f32_16x16x32_bf16(a[0], bb, acc[0][n], 0, 0, 0);
      acc[1][n] = __builtin_amdgcn_mfma_f32_16x16x32_bf16(a[1], bb, acc[1][n], 0, 0, 0);
    }
  }

  // epilogue: D layout col = lr, row = g*4 + rr
#pragma unroll
  for (int mt = 0; mt < 2; ++mt)
#pragma unroll
    for (int n = 0; n < 12; ++n)
#pragma unroll
      for (int rr = 0; rr < 4; ++rr) {
        long grow = row0 + w * 32 + mt * 16 + g * 4 + rr;
        int col = n * 16 + lr;
        unsigned short hv = f2bf(acc[mt][n][rr]);
        if (n < 4) {
          Qb[grow * 64 + col] = hv;
        } else if (n < 8) {
          Kb[grow * 64 + (col - 64)] = hv;
        } else {
          long bb_ = grow >> 11;          // / 2048
          long t = grow & 2047;
          VTb[(bb_ * 64 + (col - 128)) * 2048 + t] = hv;
        }
      }
}

// ---------------- Kernel 2: causal flash attention (barrier-free) --------------
// Per-batch K (256 KiB) + V (256 KiB) are L1/L2-resident; all 4 waves of a
// block read IDENTICAL K/V fragment addresses, so LDS staging + barriers were
// pure overhead. Each wave free-runs over its 16 q-rows.
__global__ __launch_bounds__(256, 4) void k_attn(const unsigned short* __restrict__ Qb,
                                                 const unsigned short* __restrict__ Kb,
                                                 const unsigned short* __restrict__ VTb,
                                                 float* __restrict__ out) {
  __shared__ __align__(16) unsigned short psm[4 * 16 * 64]; // per-wave P [16][64], swizzled

  const int tid = threadIdx.x;
  const int lane = tid & 63, w = tid >> 6;
  const int g = lane >> 4, lr = lane & 15;
  const int b = blockIdx.x;
  const int qt = (gridDim.y - 1) - blockIdx.y;   // longest-first dispatch
  const int qrow0 = qt * 64 + w * 16;

  const unsigned short* Kbase = Kb + (long)b * T_LEN * 64;
  const unsigned short* Vbase = VTb + (long)b * 64 * 2048;

  // Q fragments (A operand): lane holds Q[qrow0+lr][c*32 + g*8 + i]
  bf16x8 qf[2];
#pragma unroll
  for (int c = 0; c < 2; ++c)
    qf[c] = ld16(&Qb[((long)(b * T_LEN + qrow0 + lr)) * 64 + c * 32 + g * 8]);

  f32x4 o[4] = {};
  float m_r[4], l_r[4];
#pragma unroll
  for (int r = 0; r < 4; ++r) { m_r[r] = -1e30f; l_r[r] = 0.f; }

  char* pbase = (char*)psm + w * 2048;
  const int nkv = qt + 1;
  for (int t = 0; t < nkv; ++t) {
    const int kv0 = t * 64;

    // S = Q K^T   (K fragments straight from L1/L2)
    f32x4 s[4] = {};
#pragma unroll
    for (int c = 0; c < 2; ++c)
#pragma unroll
      for (int n = 0; n < 4; ++n) {
        bf16x8 kf = ld16(&Kbase[(long)(kv0 + n * 16 + lr) * 64 + c * 32 + g * 8]);
        s[n] = __builtin_amdgcn_mfma_f32_16x16x32_bf16(qf[c], kf, s[n], 0, 0, 0);
      }

    // scale + causal mask (only diagonal tile needs masking)
    const bool diag = (t == qt);
#pragma unroll
    for (int n = 0; n < 4; ++n)
#pragma unroll
      for (int r = 0; r < 4; ++r) {
        float v = s[n][r] * 0.125f;
        if (diag) {
          int col = kv0 + n * 16 + lr;
          int rowq = qrow0 + g * 4 + r;
          if (col > rowq) v = -1e30f;
        }
        s[n][r] = v;
      }

    // online softmax (rows owned per (g, r); reduce across 16 lanes = cols)
    float pr[4][4];
#pragma unroll
    for (int r = 0; r < 4; ++r) {
      float mx = fmaxf(fmaxf(s[0][r], s[1][r]), fmaxf(s[2][r], s[3][r]));
      mx = fmaxf(mx, __shfl_xor(mx, 1));
      mx = fmaxf(mx, __shfl_xor(mx, 2));
      mx = fmaxf(mx, __shfl_xor(mx, 4));
      mx = fmaxf(mx, __shfl_xor(mx, 8));
      float mn = fmaxf(m_r[r], mx);
      float sc = exp2f((m_r[r] - mn) * 1.44269504f);
      m_r[r] = mn;
      float sum = 0.f;
#pragma unroll
      for (int n = 0; n < 4; ++n) {
        float p = exp2f((s[n][r] - mn) * 1.44269504f);
        pr[n][r] = p;
        sum += p;
      }
      sum += __shfl_xor(sum, 1);
      sum += __shfl_xor(sum, 2);
      sum += __shfl_xor(sum, 4);
      sum += __shfl_xor(sum, 8);
      l_r[r] = l_r[r] * sc + sum;
#pragma unroll
      for (int n = 0; n < 4; ++n) o[n][r] *= sc;
    }

    // write P (bf16) to this wave's private LDS buffer, swizzled.
    // write->read is within ONE wave: compiler-inserted lgkmcnt orders it,
    // no barrier needed.
#pragma unroll
    for (int n = 0; n < 4; ++n)
#pragma unroll
      for (int r = 0; r < 4; ++r) {
        int rq = g * 4 + r;
        int col = n * 16 + lr;
        *(unsigned short*)(pbase + ((rq * 128 + col * 2) ^ ((rq & 7) << 4))) = f2bf(pr[n][r]);
      }

    // O += P V   (V^T fragments straight from L1/L2)
    bf16x8 pf[2];
#pragma unroll
    for (int c = 0; c < 2; ++c)
      pf[c] = ld16(pbase + ((lr * 128 + c * 64 + g * 16) ^ ((lr & 7) << 4)));
#pragma unroll
    for (int c = 0; c < 2; ++c)
#pragma unroll
      for (int n = 0; n < 4; ++n) {
        bf16x8 vf = ld16(&Vbase[(long)(n * 16 + lr) * 2048 + kv0 + c * 32 + g * 8]);
        o[n] = __builtin_amdgcn_mfma_f32_16x16x32_bf16(pf[c], vf, o[n], 0, 0, 0);
      }
  }

  // epilogue
#pragma unroll
  for (int r = 0; r < 4; ++r) {
    float inv = 1.0f / l_r[r];
#pragma unroll
    for (int n = 0; n < 4; ++n) {
      long rowg = (long)b * T_LEN + qrow0 + g * 4 + r;
      out[rowg * 64 + n * 16 + lr] = o[n][r] * inv;
    }
  }
}

// ---------------- launch -------------------------------------------------------
extern "C" void kernel_launch(void* const* d_in, const int* in_sizes, int n_in,
                              void* d_out, int out_size, void* d_ws, size_t ws_size,
                              hipStream_t stream) {
  const float* x  = (const float*)d_in[0];
  const float* Wq = (const float*)d_in[1];
  const float* Wk = (const float*)d_in[2];
  const float* Wv = (const float*)d_in[3];
  float* out = (float*)d_out;

  char* ws = (char*)d_ws;
  unsigned short* Wt3 = (unsigned short*)ws;                          // 294912 B
  unsigned short* Qb  = (unsigned short*)(ws + 0x80000);              // 8 MiB each
  unsigned short* Kb  = (unsigned short*)(ws + 0x80000 + 0x800000);
  unsigned short* VTb = (unsigned short*)(ws + 0x80000 + 0x1000000);

  k_wprep<<<dim3(288), dim3(256), 0, stream>>>(Wq, Wk, Wv, Wt3);
  k_proj<<<dim3(512), dim3(256), 0, stream>>>(x, Wt3, Qb, Kb, VTb);
  // grid: x = batch (fast), y = q-tile reversed -> heaviest q-tiles dispatch first
  k_attn<<<dim3(NBATCH, 32), dim3(256), 0, stream>>>(Qb, Kb, VTb, out);
}

// Round 3
// 182.239 us; speedup vs baseline: 1.1528x; 1.0368x over previous
//
#include <hip/hip_runtime.h>
#include <hip/hip_bf16.h>

#define T_LEN 2048
#define NBATCH 32

typedef __bf16 bf16x8 __attribute__((ext_vector_type(8)));
typedef float f32x4 __attribute__((ext_vector_type(4)));

__device__ __forceinline__ unsigned short f2bf(float f) {
  return __builtin_bit_cast(unsigned short, __float2bfloat16(f));
}
__device__ __forceinline__ unsigned int pk2(float a, float b) {
  return (unsigned int)f2bf(a) | ((unsigned int)f2bf(b) << 16);
}
__device__ __forceinline__ bf16x8 ld16(const void* p) {
  return __builtin_bit_cast(bf16x8, *(const uint4*)p);
}

// ---------------- Kernel 0: W -> Wt3 bf16 [192][384] (col-major over N) --------
__global__ __launch_bounds__(256) void k_wprep(const float* __restrict__ Wq,
                                               const float* __restrict__ Wk,
                                               const float* __restrict__ Wv,
                                               unsigned short* __restrict__ Wt3) {
  int idx = blockIdx.x * 256 + threadIdx.x;   // 0 .. 192*384-1
  if (idx >= 192 * 384) return;
  int c = idx / 384;          // output col 0..191
  int k = idx % 384;          // k dim
  const float* W = (c < 64) ? Wq : ((c < 128) ? Wk : Wv);
  Wt3[idx] = f2bf(W[k * 64 + (c & 63)]);
}

// ---------------- Kernel 1: QKV projection (MFMA bf16) -------------------------
// x fp32 [B*T][384] -> Q,K bf16 [B*T][64], VT bf16 [B][64][T]
__global__ __launch_bounds__(256) void k_proj(const float* __restrict__ x,
                                              const unsigned short* __restrict__ Wt3,
                                              unsigned short* __restrict__ Qb,
                                              unsigned short* __restrict__ Kb,
                                              unsigned short* __restrict__ VTb) {
  __shared__ __align__(16) unsigned short xs[128 * 32];   // swizzled
  __shared__ __align__(16) unsigned short wt[192 * 32];   // swizzled
  const int tid = threadIdx.x;
  const int lane = tid & 63, w = tid >> 6;
  const int g = lane >> 4, lr = lane & 15;
  const long row0 = (long)blockIdx.x * 128;

  f32x4 acc[2][12] = {};

  for (int ks = 0; ks < 12; ++ks) {
    const int k0 = ks * 32;
    __syncthreads();
    // stage x tile [128][32] fp32->bf16
    {
      int r = tid >> 1, c0 = (tid & 1) * 16;
      const float4* src = reinterpret_cast<const float4*>(&x[(row0 + r) * 384 + k0 + c0]);
      float4 f0 = src[0], f1 = src[1], f2 = src[2], f3 = src[3];
      uint4 u0, u1;
      u0.x = pk2(f0.x, f0.y); u0.y = pk2(f0.z, f0.w);
      u0.z = pk2(f1.x, f1.y); u0.w = pk2(f1.z, f1.w);
      u1.x = pk2(f2.x, f2.y); u1.y = pk2(f2.z, f2.w);
      u1.z = pk2(f3.x, f3.y); u1.w = pk2(f3.z, f3.w);
      int b0 = (r * 64 + c0 * 2) ^ ((r & 7) << 4);
      int b1 = (r * 64 + c0 * 2 + 16) ^ ((r & 7) << 4);
      *reinterpret_cast<uint4*>((char*)xs + b0) = u0;
      *reinterpret_cast<uint4*>((char*)xs + b1) = u1;
    }
    // stage Wt3 tile [192 cols][32 k]
#pragma unroll
    for (int j = 0; j < 3; ++j) {
      int chunk = tid + 256 * j;        // 0..767
      int r = chunk >> 2, c8 = chunk & 3;
      uint4 d = *reinterpret_cast<const uint4*>(&Wt3[r * 384 + k0 + c8 * 8]);
      int b = (r * 64 + c8 * 16) ^ ((r & 7) << 4);
      *reinterpret_cast<uint4*>((char*)wt + b) = d;
    }
    __syncthreads();

    bf16x8 a[2];
#pragma unroll
    for (int mt = 0; mt < 2; ++mt) {
      int r = w * 32 + mt * 16 + lr;
      a[mt] = ld16((char*)xs + ((r * 64 + g * 16) ^ ((r & 7) << 4)));
    }
#pragma unroll
    for (int n = 0; n < 12; ++n) {
      int r = n * 16 + lr;
      bf16x8 bb = ld16((char*)wt + ((r * 64 + g * 16) ^ ((r & 7) << 4)));
      acc[0][n] = __builtin_amdgcn_mfma_f32_16x16x32_bf16(a[0], bb, acc[0][n], 0, 0, 0);
      acc[1][n] = __builtin_amdgcn_mfma_f32_16x16x32_bf16(a[1], bb, acc[1][n], 0, 0, 0);
    }
  }

  // epilogue: D layout col = lr, row = g*4 + rr
#pragma unroll
  for (int mt = 0; mt < 2; ++mt)
#pragma unroll
    for (int n = 0; n < 12; ++n)
#pragma unroll
      for (int rr = 0; rr < 4; ++rr) {
        long grow = row0 + w * 32 + mt * 16 + g * 4 + rr;
        int col = n * 16 + lr;
        unsigned short hv = f2bf(acc[mt][n][rr]);
        if (n < 4) {
          Qb[grow * 64 + col] = hv;
        } else if (n < 8) {
          Kb[grow * 64 + (col - 64)] = hv;
        } else {
          long bb_ = grow >> 11;          // / 2048
          long t = grow & 2047;
          VTb[(bb_ * 64 + (col - 128)) * 2048 + t] = hv;
        }
      }
}

// ---------------- Kernel 2: causal flash attention (barrier-free) --------------
// Latency-chain-minimized: T13 defer-max (no cross-lane max reduce in steady
// state), deferred l-reduction (per-lane partials, reduced once at epilogue),
// K/V fragment loads issued at tile top so V latency hides under QK+softmax.
__global__ __launch_bounds__(256, 4) void k_attn(const unsigned short* __restrict__ Qb,
                                                 const unsigned short* __restrict__ Kb,
                                                 const unsigned short* __restrict__ VTb,
                                                 float* __restrict__ out) {
  __shared__ __align__(16) unsigned short psm[4 * 16 * 64]; // per-wave P [16][64], swizzled

  const int tid = threadIdx.x;
  const int lane = tid & 63, w = tid >> 6;
  const int g = lane >> 4, lr = lane & 15;
  const int b = blockIdx.x;
  const int qt = (gridDim.y - 1) - blockIdx.y;   // longest-first dispatch
  const int qrow0 = qt * 64 + w * 16;

  const unsigned short* Kbase = Kb + (long)b * T_LEN * 64;
  const unsigned short* Vbase = VTb + (long)b * 64 * 2048;

  // Q fragments (A operand): lane holds Q[qrow0+lr][c*32 + g*8 + i]
  bf16x8 qf[2];
#pragma unroll
  for (int c = 0; c < 2; ++c)
    qf[c] = ld16(&Qb[((long)(b * T_LEN + qrow0 + lr)) * 64 + c * 32 + g * 8]);

  f32x4 o[4] = {};
  float m_r[4], l_r[4];   // l_r: PER-LANE partial sums (reduced at epilogue)
#pragma unroll
  for (int r = 0; r < 4; ++r) { m_r[r] = -1e30f; l_r[r] = 0.f; }

  char* pbase = (char*)psm + w * 2048;
  const int nkv = qt + 1;
  for (int t = 0; t < nkv; ++t) {
    const int kv0 = t * 64;

    // issue all K and V fragment loads up front (V hides under QK+softmax)
    bf16x8 kf[2][4], vf[2][4];
#pragma unroll
    for (int c = 0; c < 2; ++c)
#pragma unroll
      for (int n = 0; n < 4; ++n) {
        kf[c][n] = ld16(&Kbase[(long)(kv0 + n * 16 + lr) * 64 + c * 32 + g * 8]);
        vf[c][n] = ld16(&Vbase[(long)(n * 16 + lr) * 2048 + kv0 + c * 32 + g * 8]);
      }

    // S = Q K^T
    f32x4 s[4] = {};
#pragma unroll
    for (int c = 0; c < 2; ++c)
#pragma unroll
      for (int n = 0; n < 4; ++n)
        s[n] = __builtin_amdgcn_mfma_f32_16x16x32_bf16(qf[c], kf[c][n], s[n], 0, 0, 0);

    // scale + causal mask (only diagonal tile needs masking)
    const bool diag = (t == qt);
#pragma unroll
    for (int n = 0; n < 4; ++n)
#pragma unroll
      for (int r = 0; r < 4; ++r) {
        float v = s[n][r] * 0.125f;
        if (diag) {
          int col = kv0 + n * 16 + lr;
          int rowq = qrow0 + g * 4 + r;
          if (col > rowq) v = -1e30f;
        }
        s[n][r] = v;
      }

    // T13 defer-max online softmax: lane-local max check; full reduce + rescale
    // only when some lane's local max exceeds m+8 (tile 0, then ~never).
    float pm[4];
#pragma unroll
    for (int r = 0; r < 4; ++r)
      pm[r] = fmaxf(fmaxf(s[0][r], s[1][r]), fmaxf(s[2][r], s[3][r]));
    bool need = false;
#pragma unroll
    for (int r = 0; r < 4; ++r) need = need || (pm[r] > m_r[r] + 8.0f);
    if (__any((int)need)) {
#pragma unroll
      for (int r = 0; r < 4; ++r) {
        float mx = pm[r];
        mx = fmaxf(mx, __shfl_xor(mx, 1));
        mx = fmaxf(mx, __shfl_xor(mx, 2));
        mx = fmaxf(mx, __shfl_xor(mx, 4));
        mx = fmaxf(mx, __shfl_xor(mx, 8));
        float mn = fmaxf(m_r[r], mx);
        float sc = exp2f((m_r[r] - mn) * 1.44269504f);
        m_r[r] = mn;
        l_r[r] *= sc;
#pragma unroll
        for (int n = 0; n < 4; ++n) o[n][r] *= sc;
      }
    }
    float pr[4][4];
#pragma unroll
    for (int r = 0; r < 4; ++r)
#pragma unroll
      for (int n = 0; n < 4; ++n) {
        float p = exp2f((s[n][r] - m_r[r]) * 1.44269504f);
        pr[n][r] = p;
        l_r[r] += p;                    // per-lane partial; no shfl here
      }

    // write P (bf16) to this wave's private LDS buffer, swizzled.
    // write->read is within ONE wave: compiler-inserted lgkmcnt orders it.
#pragma unroll
    for (int n = 0; n < 4; ++n)
#pragma unroll
      for (int r = 0; r < 4; ++r) {
        int rq = g * 4 + r;
        int col = n * 16 + lr;
        *(unsigned short*)(pbase + ((rq * 128 + col * 2) ^ ((rq & 7) << 4))) = f2bf(pr[n][r]);
      }

    // O += P V   (vf loaded at tile top, long since arrived)
    bf16x8 pf[2];
#pragma unroll
    for (int c = 0; c < 2; ++c)
      pf[c] = ld16(pbase + ((lr * 128 + c * 64 + g * 16) ^ ((lr & 7) << 4)));
#pragma unroll
    for (int c = 0; c < 2; ++c)
#pragma unroll
      for (int n = 0; n < 4; ++n)
        o[n] = __builtin_amdgcn_mfma_f32_16x16x32_bf16(pf[c], vf[c][n], o[n], 0, 0, 0);
  }

  // epilogue: reduce l across the 16 lanes of the group (once), then scale+store
#pragma unroll
  for (int r = 0; r < 4; ++r) {
    float l = l_r[r];
    l += __shfl_xor(l, 1);
    l += __shfl_xor(l, 2);
    l += __shfl_xor(l, 4);
    l += __shfl_xor(l, 8);
    float inv = 1.0f / l;
#pragma unroll
    for (int n = 0; n < 4; ++n) {
      long rowg = (long)b * T_LEN + qrow0 + g * 4 + r;
      out[rowg * 64 + n * 16 + lr] = o[n][r] * inv;
    }
  }
}

// ---------------- launch -------------------------------------------------------
extern "C" void kernel_launch(void* const* d_in, const int* in_sizes, int n_in,
                              void* d_out, int out_size, void* d_ws, size_t ws_size,
                              hipStream_t stream) {
  const float* x  = (const float*)d_in[0];
  const float* Wq = (const float*)d_in[1];
  const float* Wk = (const float*)d_in[2];
  const float* Wv = (const float*)d_in[3];
  float* out = (float*)d_out;

  char* ws = (char*)d_ws;
  unsigned short* Wt3 = (unsigned short*)ws;                          // 294912 B
  unsigned short* Qb  = (unsigned short*)(ws + 0x80000);              // 8 MiB each
  unsigned short* Kb  = (unsigned short*)(ws + 0x80000 + 0x800000);
  unsigned short* VTb = (unsigned short*)(ws + 0x80000 + 0x1000000);

  k_wprep<<<dim3(288), dim3(256), 0, stream>>>(Wq, Wk, Wv, Wt3);
  k_proj<<<dim3(512), dim3(256), 0, stream>>>(x, Wt3, Qb, Kb, VTb);
  // grid: x = batch (fast), y = q-tile reversed -> heaviest q-tiles dispatch first
  k_attn<<<dim3(NBATCH, 32), dim3(256), 0, stream>>>(Qb, Kb, VTb, out);
}

// Round 4
// 85.792 us; speedup vs baseline: 2.4487x; 2.1242x over previous
//
#include <hip/hip_runtime.h>
#include <hip/hip_bf16.h>

#define T_LEN 2048
#define NBATCH 32

typedef __bf16 bf16x8 __attribute__((ext_vector_type(8)));
typedef float f32x4 __attribute__((ext_vector_type(4)));

__device__ __forceinline__ unsigned short f2bf(float f) {
  return __builtin_bit_cast(unsigned short, __float2bfloat16(f));
}
__device__ __forceinline__ unsigned int pk2(float a, float b) {
  return (unsigned int)f2bf(a) | ((unsigned int)f2bf(b) << 16);
}
__device__ __forceinline__ bf16x8 ld16(const void* p) {
  return __builtin_bit_cast(bf16x8, *(const uint4*)p);
}
// async global->LDS, 16B per lane: lds dest = uniform base + lane*16 (linear),
// global src is PER-LANE (pre-swizzled by caller).
__device__ __forceinline__ void gl_lds16(const void* g, void* l) {
  __builtin_amdgcn_global_load_lds(
      (const __attribute__((address_space(1))) unsigned int*)g,
      (__attribute__((address_space(3))) unsigned int*)l, 16, 0, 0);
}

// ---------------- Kernel 0: W -> Wt3 bf16 [192][384] (col-major over N) --------
__global__ __launch_bounds__(256) void k_wprep(const float* __restrict__ Wq,
                                               const float* __restrict__ Wk,
                                               const float* __restrict__ Wv,
                                               unsigned short* __restrict__ Wt3) {
  int idx = blockIdx.x * 256 + threadIdx.x;   // 0 .. 192*384-1
  if (idx >= 192 * 384) return;
  int c = idx / 384;          // output col 0..191
  int k = idx % 384;          // k dim
  const float* W = (c < 64) ? Wq : ((c < 128) ? Wk : Wv);
  Wt3[idx] = f2bf(W[k * 64 + (c & 63)]);
}

// ---------------- Kernel 1: QKV projection (MFMA bf16) -------------------------
// x fp32 [B*T][384] -> Q,K bf16 [B*T][64], VT bf16 [B][64][T]
__global__ __launch_bounds__(256) void k_proj(const float* __restrict__ x,
                                              const unsigned short* __restrict__ Wt3,
                                              unsigned short* __restrict__ Qb,
                                              unsigned short* __restrict__ Kb,
                                              unsigned short* __restrict__ VTb) {
  __shared__ __align__(16) unsigned short xs[128 * 32];   // swizzled
  __shared__ __align__(16) unsigned short wt[192 * 32];   // swizzled
  const int tid = threadIdx.x;
  const int lane = tid & 63, w = tid >> 6;
  const int g = lane >> 4, lr = lane & 15;
  const long row0 = (long)blockIdx.x * 128;

  f32x4 acc[2][12] = {};

  for (int ks = 0; ks < 12; ++ks) {
    const int k0 = ks * 32;
    __syncthreads();
    // stage x tile [128][32] fp32->bf16
    {
      int r = tid >> 1, c0 = (tid & 1) * 16;
      const float4* src = reinterpret_cast<const float4*>(&x[(row0 + r) * 384 + k0 + c0]);
      float4 f0 = src[0], f1 = src[1], f2 = src[2], f3 = src[3];
      uint4 u0, u1;
      u0.x = pk2(f0.x, f0.y); u0.y = pk2(f0.z, f0.w);
      u0.z = pk2(f1.x, f1.y); u0.w = pk2(f1.z, f1.w);
      u1.x = pk2(f2.x, f2.y); u1.y = pk2(f2.z, f2.w);
      u1.z = pk2(f3.x, f3.y); u1.w = pk2(f3.z, f3.w);
      int b0 = (r * 64 + c0 * 2) ^ ((r & 7) << 4);
      int b1 = (r * 64 + c0 * 2 + 16) ^ ((r & 7) << 4);
      *reinterpret_cast<uint4*>((char*)xs + b0) = u0;
      *reinterpret_cast<uint4*>((char*)xs + b1) = u1;
    }
    // stage Wt3 tile [192 cols][32 k]
#pragma unroll
    for (int j = 0; j < 3; ++j) {
      int chunk = tid + 256 * j;        // 0..767
      int r = chunk >> 2, c8 = chunk & 3;
      uint4 d = *reinterpret_cast<const uint4*>(&Wt3[r * 384 + k0 + c8 * 8]);
      int b = (r * 64 + c8 * 16) ^ ((r & 7) << 4);
      *reinterpret_cast<uint4*>((char*)wt + b) = d;
    }
    __syncthreads();

    bf16x8 a[2];
#pragma unroll
    for (int mt = 0; mt < 2; ++mt) {
      int r = w * 32 + mt * 16 + lr;
      a[mt] = ld16((char*)xs + ((r * 64 + g * 16) ^ ((r & 7) << 4)));
    }
#pragma unroll
    for (int n = 0; n < 12; ++n) {
      int r = n * 16 + lr;
      bf16x8 bb = ld16((char*)wt + ((r * 64 + g * 16) ^ ((r & 7) << 4)));
      acc[0][n] = __builtin_amdgcn_mfma_f32_16x16x32_bf16(a[0], bb, acc[0][n], 0, 0, 0);
      acc[1][n] = __builtin_amdgcn_mfma_f32_16x16x32_bf16(a[1], bb, acc[1][n], 0, 0, 0);
    }
  }

  // epilogue: D layout col = lr, row = g*4 + rr
#pragma unroll
  for (int mt = 0; mt < 2; ++mt)
#pragma unroll
    for (int n = 0; n < 12; ++n)
#pragma unroll
      for (int rr = 0; rr < 4; ++rr) {
        long grow = row0 + w * 32 + mt * 16 + g * 4 + rr;
        int col = n * 16 + lr;
        unsigned short hv = f2bf(acc[mt][n][rr]);
        if (n < 4) {
          Qb[grow * 64 + col] = hv;
        } else if (n < 8) {
          Kb[grow * 64 + (col - 64)] = hv;
        } else {
          long bb_ = grow >> 11;          // / 2048
          long t = grow & 2047;
          VTb[(bb_ * 64 + (col - 128)) * 2048 + t] = hv;
        }
      }
}

// ---------------- Kernel 2: causal flash attention, 2-phase LDS pipeline -------
// T3-minimum pattern: K/V tiles double-buffered in LDS via global_load_lds
// (16B, linear dest); global SOURCE pre-swizzled so the round-1-verified
// swizzled ds_read_b128 formulas apply (rule #21: both-sides-or-neither).
// Stage(t+1) issued at loop top; one __syncthreads per tile (compiler's
// auto vmcnt-drain before s_barrier is exactly the pipeline fence we need).
__global__ __launch_bounds__(256, 4) void k_attn(const unsigned short* __restrict__ Qb,
                                                 const unsigned short* __restrict__ Kb,
                                                 const unsigned short* __restrict__ VTb,
                                                 float* __restrict__ out) {
  __shared__ __align__(16) char ksm[2 * 8192];              // K tiles [64][64]
  __shared__ __align__(16) char vsm[2 * 8192];              // V^T tiles [64][64]
  __shared__ __align__(16) unsigned short psm[4 * 16 * 64]; // per-wave P, swizzled

  const int tid = threadIdx.x;
  const int lane = tid & 63, w = tid >> 6;
  const int g = lane >> 4, lr = lane & 15;
  const int b = blockIdx.x;
  const int qt = (gridDim.y - 1) - blockIdx.y;   // longest-first dispatch
  const int qrow0 = qt * 64 + w * 16;

  const char* Kg = (const char*)(Kb + (long)b * T_LEN * 64);   // row stride 128 B
  const char* Vg = (const char*)(VTb + (long)b * 64 * 2048);   // row stride 4096 B

  // staging address components: lane writes LDS bytes [16*lane,16*lane+16)
  // of its wave's 2048-B segment; row = w*16 + p*8 + (lane>>3); source byte
  // within row pre-swizzled: ((lane&7) ^ (lane>>3)) << 4.
  const int lrow = lane >> 3;
  const int lsw = (((lane & 7) ^ lrow) << 4);

  // Q fragments (A operand): lane holds Q[qrow0+lr][c*32 + g*8 + i]
  bf16x8 qf[2];
#pragma unroll
  for (int c = 0; c < 2; ++c)
    qf[c] = ld16(&Qb[((long)(b * T_LEN + qrow0 + lr)) * 64 + c * 32 + g * 8]);

  f32x4 o[4] = {};
  float m_r[4], l_r[4];   // l_r: PER-LANE partial sums (reduced at epilogue)
#pragma unroll
  for (int r = 0; r < 4; ++r) { m_r[r] = -1e30f; l_r[r] = 0.f; }

  char* pbase = (char*)psm + w * 2048;
  const int nkv = qt + 1;

  // ---- prologue: stage tile 0 into buffer 0
  {
    const char* gk = Kg + ((long)(0 + w * 16 + lrow)) * 128 + lsw;
    const char* gv = Vg + ((long)(w * 16 + lrow)) * 4096 + lsw;
    char* kb = ksm + w * 2048;
    char* vb = vsm + w * 2048;
    gl_lds16(gk, kb);             gl_lds16(gk + 8 * 128, kb + 1024);
    gl_lds16(gv, vb);             gl_lds16(gv + 8 * 4096, vb + 1024);
  }
  __syncthreads();   // compiler drains vmcnt(0) before s_barrier

  int cur = 0;
  for (int t = 0; t < nkv; ++t) {
    const int kv0 = t * 64;

    // ---- issue next tile's stage into the other buffer (latency hides under
    // this tile's compute; drained by the end-of-iteration barrier)
    if (t + 1 < nkv) {
      const int kv1 = kv0 + 64;
      const char* gk = Kg + ((long)(kv1 + w * 16 + lrow)) * 128 + lsw;
      const char* gv = Vg + ((long)(w * 16 + lrow)) * 4096 + (long)kv1 * 2 + lsw;
      char* kb = ksm + (cur ^ 1) * 8192 + w * 2048;
      char* vb = vsm + (cur ^ 1) * 8192 + w * 2048;
      gl_lds16(gk, kb);           gl_lds16(gk + 8 * 128, kb + 1024);
      gl_lds16(gv, vb);           gl_lds16(gv + 8 * 4096, vb + 1024);
    }

    char* kt = ksm + cur * 8192;
    char* vt = vsm + cur * 8192;

    // ---- S = Q K^T (K from LDS, swizzled reads)
    f32x4 s[4] = {};
    __builtin_amdgcn_s_setprio(1);
#pragma unroll
    for (int c = 0; c < 2; ++c)
#pragma unroll
      for (int n = 0; n < 4; ++n) {
        int r = n * 16 + lr;
        bf16x8 kf = ld16(kt + ((r * 128 + c * 64 + g * 16) ^ ((r & 7) << 4)));
        s[n] = __builtin_amdgcn_mfma_f32_16x16x32_bf16(qf[c], kf, s[n], 0, 0, 0);
      }
    __builtin_amdgcn_s_setprio(0);

    // ---- scale + causal mask (only diagonal tile)
    const bool diag = (t == qt);
#pragma unroll
    for (int n = 0; n < 4; ++n)
#pragma unroll
      for (int r = 0; r < 4; ++r) {
        float v = s[n][r] * 0.125f;
        if (diag) {
          int col = kv0 + n * 16 + lr;
          int rowq = qrow0 + g * 4 + r;
          if (col > rowq) v = -1e30f;
        }
        s[n][r] = v;
      }

    // ---- T13 defer-max online softmax
    float pm[4];
#pragma unroll
    for (int r = 0; r < 4; ++r)
      pm[r] = fmaxf(fmaxf(s[0][r], s[1][r]), fmaxf(s[2][r], s[3][r]));
    bool need = false;
#pragma unroll
    for (int r = 0; r < 4; ++r) need = need || (pm[r] > m_r[r] + 8.0f);
    if (__any((int)need)) {
#pragma unroll
      for (int r = 0; r < 4; ++r) {
        float mx = pm[r];
        mx = fmaxf(mx, __shfl_xor(mx, 1));
        mx = fmaxf(mx, __shfl_xor(mx, 2));
        mx = fmaxf(mx, __shfl_xor(mx, 4));
        mx = fmaxf(mx, __shfl_xor(mx, 8));
        float mn = fmaxf(m_r[r], mx);
        float sc = exp2f((m_r[r] - mn) * 1.44269504f);
        m_r[r] = mn;
        l_r[r] *= sc;
#pragma unroll
        for (int n = 0; n < 4; ++n) o[n][r] *= sc;
      }
    }
    float pr[4][4];
#pragma unroll
    for (int r = 0; r < 4; ++r)
#pragma unroll
      for (int n = 0; n < 4; ++n) {
        float p = exp2f((s[n][r] - m_r[r]) * 1.44269504f);
        pr[n][r] = p;
        l_r[r] += p;                    // per-lane partial; no shfl here
      }

    // ---- P -> LDS (per-wave buffer; wave-internal write->read, no barrier)
#pragma unroll
    for (int n = 0; n < 4; ++n)
#pragma unroll
      for (int r = 0; r < 4; ++r) {
        int rq = g * 4 + r;
        int col = n * 16 + lr;
        *(unsigned short*)(pbase + ((rq * 128 + col * 2) ^ ((rq & 7) << 4))) = f2bf(pr[n][r]);
      }

    // ---- O += P V (V from LDS)
    bf16x8 pf[2];
#pragma unroll
    for (int c = 0; c < 2; ++c)
      pf[c] = ld16(pbase + ((lr * 128 + c * 64 + g * 16) ^ ((lr & 7) << 4)));
    __builtin_amdgcn_s_setprio(1);
#pragma unroll
    for (int c = 0; c < 2; ++c)
#pragma unroll
      for (int n = 0; n < 4; ++n) {
        int r = n * 16 + lr;
        bf16x8 vf = ld16(vt + ((r * 128 + c * 64 + g * 16) ^ ((r & 7) << 4)));
        o[n] = __builtin_amdgcn_mfma_f32_16x16x32_bf16(pf[c], vf, o[n], 0, 0, 0);
      }
    __builtin_amdgcn_s_setprio(0);

    __syncthreads();   // drains vmcnt(0): stage(t+1) complete; all waves done reading
    cur ^= 1;
  }

  // epilogue: reduce l across the 16 lanes of the group (once), then scale+store
#pragma unroll
  for (int r = 0; r < 4; ++r) {
    float l = l_r[r];
    l += __shfl_xor(l, 1);
    l += __shfl_xor(l, 2);
    l += __shfl_xor(l, 4);
    l += __shfl_xor(l, 8);
    float inv = 1.0f / l;
#pragma unroll
    for (int n = 0; n < 4; ++n) {
      long rowg = (long)b * T_LEN + qrow0 + g * 4 + r;
      out[rowg * 64 + n * 16 + lr] = o[n][r] * inv;
    }
  }
}

// ---------------- launch -------------------------------------------------------
extern "C" void kernel_launch(void* const* d_in, const int* in_sizes, int n_in,
                              void* d_out, int out_size, void* d_ws, size_t ws_size,
                              hipStream_t stream) {
  const float* x  = (const float*)d_in[0];
  const float* Wq = (const float*)d_in[1];
  const float* Wk = (const float*)d_in[2];
  const float* Wv = (const float*)d_in[3];
  float* out = (float*)d_out;

  char* ws = (char*)d_ws;
  unsigned short* Wt3 = (unsigned short*)ws;                          // 294912 B
  unsigned short* Qb  = (unsigned short*)(ws + 0x80000);              // 8 MiB each
  unsigned short* Kb  = (unsigned short*)(ws + 0x80000 + 0x800000);
  unsigned short* VTb = (unsigned short*)(ws + 0x80000 + 0x1000000);

  k_wprep<<<dim3(288), dim3(256), 0, stream>>>(Wq, Wk, Wv, Wt3);
  k_proj<<<dim3(512), dim3(256), 0, stream>>>(x, Wt3, Qb, Kb, VTb);
  // grid: x = batch (fast), y = q-tile reversed -> heaviest q-tiles dispatch first
  k_attn<<<dim3(NBATCH, 32), dim3(256), 0, stream>>>(Qb, Kb, VTb, out);
}